// Round 4
// baseline (3735.738 us; speedup 1.0000x reference)
//
#include <hip/hip_runtime.h>
#include <stdint.h>

// Problem constants
#define B_   2
#define S_   2048
#define D_   1024
#define H_   16
#define DK_  64
#define DFF_ 4096
#define M_   (B_ * S_)   // 4096 rows total

typedef unsigned short u16;
typedef unsigned int   u32;

// ---------- bf16 <-> f32 helpers (manual, RNE) ----------
__device__ __forceinline__ float b2f(u16 u) {
  union { u32 i; float f; } z; z.i = ((u32)u) << 16; return z.f;
}
__device__ __forceinline__ u16 f2b(float f) {
  union { float f; u32 i; } z; z.f = f;
  u32 x = z.i;
  u32 r = (x + 0x7fffu + ((x >> 16) & 1u)) >> 16;
  return (u16)r;
}
__device__ __forceinline__ void unpack8(uint4 v, float* f) {
  f[0] = b2f(v.x & 0xffffu); f[1] = b2f(v.x >> 16);
  f[2] = b2f(v.y & 0xffffu); f[3] = b2f(v.y >> 16);
  f[4] = b2f(v.z & 0xffffu); f[5] = b2f(v.z >> 16);
  f[6] = b2f(v.w & 0xffffu); f[7] = b2f(v.w >> 16);
}
__device__ __forceinline__ uint4 pack8(const float* f) {
  uint4 v;
  v.x = (u32)f2b(f[0]) | ((u32)f2b(f[1]) << 16);
  v.y = (u32)f2b(f[2]) | ((u32)f2b(f[3]) << 16);
  v.z = (u32)f2b(f[4]) | ((u32)f2b(f[5]) << 16);
  v.w = (u32)f2b(f[6]) | ((u32)f2b(f[7]) << 16);
  return v;
}

// load/store 8 consecutive elems as fp32, bf16 or fp32 backing
__device__ __forceinline__ void load8(const u16* p, float* f) {
  uint4 v = *(const uint4*)p;
  unpack8(v, f);
}
__device__ __forceinline__ void load8(const float* p, float* f) {
  float4 a = *(const float4*)p;
  float4 b = *(const float4*)(p + 4);
  f[0] = a.x; f[1] = a.y; f[2] = a.z; f[3] = a.w;
  f[4] = b.x; f[5] = b.y; f[6] = b.z; f[7] = b.w;
}
__device__ __forceinline__ void store8(u16* p, const float* f) {
  *(uint4*)p = pack8(f);
}
__device__ __forceinline__ void store8(float* p, const float* f) {
  *(float4*)p       = make_float4(f[0], f[1], f[2], f[3]);
  *(float4*)(p + 4) = make_float4(f[4], f[5], f[6], f[7]);
}

// ---------- GEMM: C[M,N] = A[M,K] @ W[K,N] + bias (+res) (+ReLU) ----------
// A: fp32 or bf16. W/bias: fp32 (harness inputs). C/res: fp32 or bf16.
// fp32 accumulate. 128x128 tile, BK=16, 256 threads, 8x8 micro-tile.
template<bool RELU, bool RES, typename TA, typename TO>
__global__ __launch_bounds__(256)
void gemm_bias(const TA* __restrict__ A, const float* __restrict__ W,
               const float* __restrict__ bias, const TO* __restrict__ res,
               TO* __restrict__ C, int M, int N, int K)
{
  __shared__ float As[16][132];   // As[k][m], pad 128->132 (16B-aligned rows)
  __shared__ float Bs[16][128];   // Bs[k][n]

  const int tid  = threadIdx.x;
  const int tx   = tid & 15;      // col group (8 cols each)
  const int ty   = tid >> 4;      // row group (8 rows each)
  const int row0 = blockIdx.y * 128;
  const int col0 = blockIdx.x * 128;

  float acc[8][8];
#pragma unroll
  for (int i = 0; i < 8; ++i)
#pragma unroll
    for (int j = 0; j < 8; ++j) acc[i][j] = 0.f;

  const int ar = tid >> 1;          // 0..127
  const int ac = (tid & 1) * 8;     // 0 or 8
  const int br = tid >> 4;          // 0..15
  const int bc = (tid & 15) * 8;    // 0..120

  for (int k0 = 0; k0 < K; k0 += 16) {
    float af[8], bf[8];
    load8(A + (size_t)(row0 + ar) * K + (k0 + ac), af);
    load8(W + (size_t)(k0 + br) * N + (col0 + bc), bf);
#pragma unroll
    for (int j = 0; j < 8; ++j) As[ac + j][ar] = af[j];
#pragma unroll
    for (int j = 0; j < 8; ++j) Bs[br][bc + j] = bf[j];
    __syncthreads();

#pragma unroll
    for (int kk = 0; kk < 16; ++kk) {
      float a[8], b[8];
      *(float4*)&a[0] = *(const float4*)&As[kk][ty * 8];
      *(float4*)&a[4] = *(const float4*)&As[kk][ty * 8 + 4];
      *(float4*)&b[0] = *(const float4*)&Bs[kk][tx * 8];
      *(float4*)&b[4] = *(const float4*)&Bs[kk][tx * 8 + 4];
#pragma unroll
      for (int i = 0; i < 8; ++i)
#pragma unroll
        for (int j = 0; j < 8; ++j)
          acc[i][j] = fmaf(a[i], b[j], acc[i][j]);
    }
    __syncthreads();
  }

  float bvals[8];
  load8(bias + col0 + tx * 8, bvals);
#pragma unroll
  for (int i = 0; i < 8; ++i) {
    const int r = row0 + ty * 8 + i;
    float o[8];
    float rv[8];
    if (RES) load8(res + (size_t)r * N + col0 + tx * 8, rv);
#pragma unroll
    for (int j = 0; j < 8; ++j) {
      float vv = acc[i][j] + bvals[j];
      if (RELU) vv = fmaxf(vv, 0.f);
      if (RES)  vv += rv[j];
      o[j] = vv;
    }
    store8(C + (size_t)r * N + col0 + tx * 8, o);
  }
}

// ---------- Fused attention with head-axis softmax (bf16 q/k/v/ctx) ----------
// scores[b,h,q,k] = (q_row_h . k_row_h)/8 ; attn = softmax over h (16 heads);
// ctx[b,q,h*64+d] = sum_k attn[b,h,q,k] * v[b,k,h*64+d]
// One wave per q-row. Lane l: head h = l>>2, quarter = l&3 (16 contiguous
// elems). Quad sum (xor 1,2) -> per-head dot on all 4 lanes; butterfly over
// lane bits 2..5 (xor 4,8,16,32) -> max/sum across the 16 heads, each head
// counted exactly once (bits 0-1 held fixed).
__global__ __launch_bounds__(256)
void attention(const u16* __restrict__ q, const u16* __restrict__ k,
               const u16* __restrict__ v, u16* __restrict__ ctx)
{
  const int wave = threadIdx.x >> 6;
  const int lane = threadIdx.x & 63;
  const int qrow = blockIdx.x * 4 + wave;       // 0..M_-1
  const int b    = qrow / S_;
  const int off  = (lane >> 2) * 64 + (lane & 3) * 16;  // this lane's 16 cols

  float qr[16];
  {
    const u16* qp = q + (size_t)qrow * D_ + off;
    load8(qp, qr);
    load8(qp + 8, qr + 8);
  }
  float acc[16];
#pragma unroll
  for (int i = 0; i < 16; ++i) acc[i] = 0.f;

  const u16* kb = k + (size_t)b * S_ * D_;
  const u16* vb = v + (size_t)b * S_ * D_;

  for (int t = 0; t < S_; ++t) {
    const u16* kp = kb + (size_t)t * D_ + off;
    float kf[16];
    load8(kp, kf);
    load8(kp + 8, kf + 8);
    float dot = 0.f;
#pragma unroll
    for (int j = 0; j < 16; ++j) dot = fmaf(qr[j], kf[j], dot);
    dot += __shfl_xor(dot, 1);
    dot += __shfl_xor(dot, 2);
    float s = dot * 0.125f;    // 1/sqrt(64)
    float m = s;
    m = fmaxf(m, __shfl_xor(m, 4));
    m = fmaxf(m, __shfl_xor(m, 8));
    m = fmaxf(m, __shfl_xor(m, 16));
    m = fmaxf(m, __shfl_xor(m, 32));
    float e = __expf(s - m);
    float sum = e;
    sum += __shfl_xor(sum, 4);
    sum += __shfl_xor(sum, 8);
    sum += __shfl_xor(sum, 16);
    sum += __shfl_xor(sum, 32);
    const float w = e / sum;   // attn weight for head h at (q,t)

    const u16* vp = vb + (size_t)t * D_ + off;
    float vf[16];
    load8(vp, vf);
    load8(vp + 8, vf + 8);
#pragma unroll
    for (int j = 0; j < 16; ++j) acc[j] = fmaf(w, vf[j], acc[j]);
  }

  u16* cp = ctx + (size_t)qrow * D_ + off;
  store8(cp, acc);
  store8(cp + 8, acc + 8);
}

// ---------- (x [+ y]) -> LayerNorm (D=1024, one block per row) ----------
__device__ __forceinline__ float block_sum(float vv, float* sm) {
#pragma unroll
  for (int o = 32; o > 0; o >>= 1) vv += __shfl_down(vv, o);
  __syncthreads();
  if ((threadIdx.x & 63) == 0) sm[threadIdx.x >> 6] = vv;
  __syncthreads();
  return sm[0] + sm[1] + sm[2] + sm[3];
}

// TX: fp32 or bf16 input. y (optional): bf16. g/beta: fp32. TO: output dtype.
template<typename TX, bool HAS_Y, typename TO>
__global__ __launch_bounds__(256)
void add_ln(const TX* __restrict__ x, const u16* __restrict__ y,
            const float* __restrict__ g, const float* __restrict__ bta,
            TO* __restrict__ out)
{
  __shared__ float sm[4];
  const int row = blockIdx.x;
  const int t   = threadIdx.x;   // 4 elems per thread
  const size_t base = (size_t)row * D_ + t * 4;

  float s[4];
  if (sizeof(TX) == 4) {
    float4 xv = *(const float4*)((const float*)x + base);
    s[0] = xv.x; s[1] = xv.y; s[2] = xv.z; s[3] = xv.w;
  } else {
    uint2 xv = *(const uint2*)((const u16*)x + base);
    s[0] = b2f(xv.x & 0xffffu);
    s[1] = b2f(xv.x >> 16);
    s[2] = b2f(xv.y & 0xffffu);
    s[3] = b2f(xv.y >> 16);
  }
  if (HAS_Y) {
    uint2 yv = *(const uint2*)(y + base);
    s[0] += b2f(yv.x & 0xffffu);
    s[1] += b2f(yv.x >> 16);
    s[2] += b2f(yv.y & 0xffffu);
    s[3] += b2f(yv.y >> 16);
  }

  float loc = s[0] + s[1] + s[2] + s[3];
  float tot = block_sum(loc, sm);
  float mean = tot * (1.f / 1024.f);
  float d0 = s[0] - mean, d1 = s[1] - mean, d2 = s[2] - mean, d3 = s[3] - mean;
  float sq = d0 * d0 + d1 * d1 + d2 * d2 + d3 * d3;
  float tv = block_sum(sq, sm);
  float rstd = rsqrtf(tv * (1.f / 1024.f) + 1e-5f);

  float4 gv = *(const float4*)(g + t * 4);
  float4 bv = *(const float4*)(bta + t * 4);
  float o0 = d0 * rstd * gv.x + bv.x;
  float o1 = d1 * rstd * gv.y + bv.y;
  float o2 = d2 * rstd * gv.z + bv.z;
  float o3 = d3 * rstd * gv.w + bv.w;
  if (sizeof(TO) == 4) {
    *(float4*)((float*)out + base) = make_float4(o0, o1, o2, o3);
  } else {
    uint2 ov;
    ov.x = (u32)f2b(o0) | ((u32)f2b(o1) << 16);
    ov.y = (u32)f2b(o2) | ((u32)f2b(o3) << 16);
    *(uint2*)((u16*)out + base) = ov;
  }
}

// ---------- launch ----------
// Inputs fp32, OUTPUT fp32 (reference output dtype is float32; rounds 1-3
// dtype forensics: bf16-read of inputs => NaN, bf16-write of output => finite
// ~1.4x-max error). Intermediates bf16 in ws (within 2% tol). Peak ws =
// 4 * M*D * 2B = 33.55 MB.
//   slot0: q   -> ao  -> h1[0]
//   slot1: k   -> h1[1]
//   slot2: v   -> h1[2]
//   slot3: ctx -> h1[3]
//   d_out(fp32): x1 -> z (FFN2 adds x1 residual in-place) -> final LN in-place
extern "C" void kernel_launch(void* const* d_in, const int* in_sizes, int n_in,
                              void* d_out, int out_size, void* d_ws, size_t ws_size,
                              hipStream_t stream) {
  const float* x     = (const float*)d_in[0];
  const float* wq    = (const float*)d_in[1];
  const float* bq    = (const float*)d_in[2];
  const float* wk    = (const float*)d_in[3];
  const float* bk    = (const float*)d_in[4];
  const float* wv    = (const float*)d_in[5];
  const float* bv    = (const float*)d_in[6];
  const float* wo    = (const float*)d_in[7];
  const float* bo    = (const float*)d_in[8];
  const float* g1    = (const float*)d_in[9];
  const float* beta1 = (const float*)d_in[10];
  const float* w1    = (const float*)d_in[11];
  const float* b1    = (const float*)d_in[12];
  const float* w2    = (const float*)d_in[13];
  const float* b2    = (const float*)d_in[14];
  const float* g2    = (const float*)d_in[15];
  const float* beta2 = (const float*)d_in[16];
  float* outF = (float*)d_out;

  u16* ws = (u16*)d_ws;
  const size_t MD = (size_t)M_ * D_;   // 4,194,304 elems (8 MB bf16)
  u16* q   = ws + 0 * MD;
  u16* kb  = ws + 1 * MD;
  u16* vb  = ws + 2 * MD;
  u16* ctx = ws + 3 * MD;
  u16* ao  = ws + 0 * MD;   // reuse q slot (q dead after attention)
  float* x1 = outF;         // x1 lives in d_out (fp32)
  u16* h1  = ws + 0 * MD;   // 4 contiguous slots (all dead after add_ln #1)
  float* z  = outF;         // FFN2 writes z = x1 + ff in-place over x1

  dim3 blk(256);
  // QKV projections (A = x fp32 -> bf16 ws)
  gemm_bias<false, false><<<dim3(D_ / 128, M_ / 128), blk, 0, stream>>>(x, wq, bq, (const u16*)nullptr, q,  M_, D_, D_);
  gemm_bias<false, false><<<dim3(D_ / 128, M_ / 128), blk, 0, stream>>>(x, wk, bk, (const u16*)nullptr, kb, M_, D_, D_);
  gemm_bias<false, false><<<dim3(D_ / 128, M_ / 128), blk, 0, stream>>>(x, wv, bv, (const u16*)nullptr, vb, M_, D_, D_);
  // fused attention (head-axis softmax), bf16 -> bf16
  attention<<<dim3(M_ / 4), blk, 0, stream>>>(q, kb, vb, ctx);
  // output projection (A = ctx bf16 -> bf16 ws, over q slot)
  gemm_bias<false, false><<<dim3(D_ / 128, M_ / 128), blk, 0, stream>>>(ctx, wo, bo, (const u16*)nullptr, ao, M_, D_, D_);
  // x1 = LN(x + attn_out) -> d_out (fp32)
  add_ln<float, true, float><<<dim3(M_), blk, 0, stream>>>(x, ao, g1, beta1, x1);
  // FFN1: h1 = relu(x1 @ w1 + b1) -> bf16 slots 0..3
  gemm_bias<true, false><<<dim3(DFF_ / 128, M_ / 128), blk, 0, stream>>>(x1, w1, b1, (const u16*)nullptr, h1, M_, DFF_, D_);
  // FFN2 (+ residual x1 fused): z = h1 @ w2 + b2 + x1, in-place over d_out (fp32)
  gemm_bias<false, true><<<dim3(D_ / 128, M_ / 128), blk, 0, stream>>>(h1, w2, b2, (const float*)x1, z, M_, D_, DFF_);
  // out = LN(z), in-place on d_out (fp32)
  add_ln<float, false, float><<<dim3(M_), blk, 0, stream>>>(z, (const u16*)nullptr, g2, beta2, outF);
}

// Round 7
// 2387.197 us; speedup vs baseline: 1.5649x; 1.5649x over previous
//
#include <hip/hip_runtime.h>
#include <stdint.h>

// Problem constants
#define B_   2
#define S_   2048
#define D_   1024
#define H_   16
#define DK_  64
#define DFF_ 4096
#define M_   (B_ * S_)   // 4096 rows total

typedef unsigned short u16;
typedef unsigned int   u32;
typedef __attribute__((ext_vector_type(8))) short short8;  // 8 bf16 (4 VGPRs)
typedef __attribute__((ext_vector_type(4))) float f32x4;   // MFMA C/D

// ---------- bf16 <-> f32 helpers ----------
__device__ __forceinline__ float b2f(u16 u) {
  union { u32 i; float f; } z; z.i = ((u32)u) << 16; return z.f;
}
__device__ __forceinline__ u16 f2b(float f) {
  union { float f; u32 i; } z; z.f = f;
  u32 x = z.i;
  u32 r = (x + 0x7fffu + ((x >> 16) & 1u)) >> 16;
  return (u16)r;
}
__device__ __forceinline__ void unpack8(uint4 v, float* f) {
  f[0] = b2f(v.x & 0xffffu); f[1] = b2f(v.x >> 16);
  f[2] = b2f(v.y & 0xffffu); f[3] = b2f(v.y >> 16);
  f[4] = b2f(v.z & 0xffffu); f[5] = b2f(v.z >> 16);
  f[6] = b2f(v.w & 0xffffu); f[7] = b2f(v.w >> 16);
}
__device__ __forceinline__ uint4 pack8(const float* f) {
  uint4 v;
  v.x = (u32)f2b(f[0]) | ((u32)f2b(f[1]) << 16);
  v.y = (u32)f2b(f[2]) | ((u32)f2b(f[3]) << 16);
  v.z = (u32)f2b(f[4]) | ((u32)f2b(f[5]) << 16);
  v.w = (u32)f2b(f[6]) | ((u32)f2b(f[7]) << 16);
  return v;
}
__device__ __forceinline__ void load8(const u16* p, float* f) {
  uint4 v = *(const uint4*)p;
  unpack8(v, f);
}
__device__ __forceinline__ void load8(const float* p, float* f) {
  float4 a = *(const float4*)p;
  float4 b = *(const float4*)(p + 4);
  f[0] = a.x; f[1] = a.y; f[2] = a.z; f[3] = a.w;
  f[4] = b.x; f[5] = b.y; f[6] = b.z; f[7] = b.w;
}
__device__ __forceinline__ void store8(u16* p, const float* f) {
  *(uint4*)p = pack8(f);
}
__device__ __forceinline__ void store8(float* p, const float* f) {
  *(float4*)p       = make_float4(f[0], f[1], f[2], f[3]);
  *(float4*)(p + 4) = make_float4(f[4], f[5], f[6], f[7]);
}

// ---------- GEMM: C[M,N] = (A[M,K] @ W[K,N] + bias)*oscale (+res) (+ReLU) ----------
// A: fp32 or bf16. W/bias: fp32. C/res: fp32 or bf16. fp32 accumulate.
// 128x128 tile, BK=16, 256 threads, 8x8 micro-tile.
template<bool RELU, bool RES, typename TA, typename TO>
__global__ __launch_bounds__(256)
void gemm_bias(const TA* __restrict__ A, const float* __restrict__ W,
               const float* __restrict__ bias, const TO* __restrict__ res,
               TO* __restrict__ C, int M, int N, int K, float oscale)
{
  __shared__ float As[16][132];
  __shared__ float Bs[16][128];

  const int tid  = threadIdx.x;
  const int tx   = tid & 15;
  const int ty   = tid >> 4;
  const int row0 = blockIdx.y * 128;
  const int col0 = blockIdx.x * 128;

  float acc[8][8];
#pragma unroll
  for (int i = 0; i < 8; ++i)
#pragma unroll
    for (int j = 0; j < 8; ++j) acc[i][j] = 0.f;

  const int ar = tid >> 1;
  const int ac = (tid & 1) * 8;
  const int br = tid >> 4;
  const int bc = (tid & 15) * 8;

  for (int k0 = 0; k0 < K; k0 += 16) {
    float af[8], bf[8];
    load8(A + (size_t)(row0 + ar) * K + (k0 + ac), af);
    load8(W + (size_t)(k0 + br) * N + (col0 + bc), bf);
#pragma unroll
    for (int j = 0; j < 8; ++j) As[ac + j][ar] = af[j];
#pragma unroll
    for (int j = 0; j < 8; ++j) Bs[br][bc + j] = bf[j];
    __syncthreads();

#pragma unroll
    for (int kk = 0; kk < 16; ++kk) {
      float a[8], b[8];
      *(float4*)&a[0] = *(const float4*)&As[kk][ty * 8];
      *(float4*)&a[4] = *(const float4*)&As[kk][ty * 8 + 4];
      *(float4*)&b[0] = *(const float4*)&Bs[kk][tx * 8];
      *(float4*)&b[4] = *(const float4*)&Bs[kk][tx * 8 + 4];
#pragma unroll
      for (int i = 0; i < 8; ++i)
#pragma unroll
        for (int j = 0; j < 8; ++j)
          acc[i][j] = fmaf(a[i], b[j], acc[i][j]);
    }
    __syncthreads();
  }

  float bvals[8];
  load8(bias + col0 + tx * 8, bvals);
#pragma unroll
  for (int i = 0; i < 8; ++i) {
    const int r = row0 + ty * 8 + i;
    float o[8];
    float rv[8];
    if (RES) load8(res + (size_t)r * N + col0 + tx * 8, rv);
#pragma unroll
    for (int j = 0; j < 8; ++j) {
      float vv = (acc[i][j] + bvals[j]) * oscale;
      if (RELU) vv = fmaxf(vv, 0.f);
      if (RES)  vv += rv[j];
      o[j] = vv;
    }
    store8(C + (size_t)r * N + col0 + tx * 8, o);
  }
}

// ---------- MFMA attention with head-axis softmax ----------
// Block = 16 q-rows, 1024 threads (16 waves), grid 256.
// Per 16-t tile:
//  Phase A: all waves stage V tile -> LDS; wave 0 computes S_h = Q_h K_h^T
//           for all 16 heads via mfma_f32_16x16x32_bf16 (frags straight from
//           global), head-axis softmax entirely in-register (the 16 head
//           values for a (q,t) live in the same lane+reg across the 16
//           accumulators), writes weights to LDS bf16 [h][q][40] (k>=16
//           zeroed once -> upper-K zeros make the K=32 PV MFMA exact).
//  Phase B: wave w computes ctx for head h=w with 4 MFMAs (16-col tiles).
// MFMA layouts (guide-verified): A[m=lane&15][k=quad*8+j],
// B[k=quad*8+j][n=lane&15], C/D col=lane&15, row=quad*4+reg.
#define TP_ 40
__global__ __launch_bounds__(1024)
void attention_mfma(const u16* __restrict__ q, const u16* __restrict__ k,
                    const u16* __restrict__ v, u16* __restrict__ ctx)
{
  __shared__ __align__(16) u16 Vs[16][1028];       // 32,896 B
  __shared__ __align__(16) u16 Ws[16][16][TP_];    // 20,480 B

  const int tid  = threadIdx.x;
  const int wave = tid >> 6;
  const int lane = tid & 63;
  const int lo16 = lane & 15;
  const int quad = lane >> 4;

  const int blk   = blockIdx.x;
  const int qrow0 = blk * 16;          // q-tiles never straddle batches
  const int batch = blk >> 7;
  const u16* kbp = k + (size_t)batch * S_ * D_;
  const u16* vbp = v + (size_t)batch * S_ * D_;

  // zero all of Ws once (k<16 rewritten every tile; k in [16,40) stays 0)
  {
    u32* wp = (u32*)&Ws[0][0][0];
    const int n = 16 * 16 * TP_ / 2;
    for (int i = tid; i < n; i += 1024) wp[i] = 0;
  }

  f32x4 cacc[4];
#pragma unroll
  for (int i = 0; i < 4; ++i) cacc[i] = (f32x4){0.f, 0.f, 0.f, 0.f};

  // V staging map: row = tid&15, colgrp = tid>>4
  const int strow = tid & 15;
  const int stcol = (tid >> 4) * 16;

  // wave-0 per-lane fragment base for Q
  const u16* qrow = q + (size_t)(qrow0 + lo16) * D_ + quad * 8;

  __syncthreads();

  for (int t0 = 0; t0 < S_; t0 += 16) {
    // ---- Phase A: stage V + (wave 0) scores & softmax ----
    {
      const u16* gp = vbp + (size_t)(t0 + strow) * D_ + stcol;
      uint4 a = *(const uint4*)gp;
      uint4 b = *(const uint4*)(gp + 8);
      u16* lp = &Vs[strow][stcol];
      *(uint2*)(lp)      = make_uint2(a.x, a.y);
      *(uint2*)(lp + 4)  = make_uint2(a.z, a.w);
      *(uint2*)(lp + 8)  = make_uint2(b.x, b.y);
      *(uint2*)(lp + 12) = make_uint2(b.z, b.w);
    }
    if (wave == 0) {
      const u16* krow = kbp + (size_t)(t0 + lo16) * D_ + quad * 8;
      f32x4 S[16];
#pragma unroll
      for (int h = 0; h < 16; ++h) {
        short8 a0 = *(const short8*)(qrow + h * 64);
        short8 b0 = *(const short8*)(krow + h * 64);
        short8 a1 = *(const short8*)(qrow + h * 64 + 32);
        short8 b1 = *(const short8*)(krow + h * 64 + 32);
        f32x4 s = (f32x4){0.f, 0.f, 0.f, 0.f};
        s = __builtin_amdgcn_mfma_f32_16x16x32_bf16(a0, b0, s, 0, 0, 0);
        s = __builtin_amdgcn_mfma_f32_16x16x32_bf16(a1, b1, s, 0, 0, 0);
        S[h] = s;
      }
      // in-register softmax over the 16 heads (scale pre-folded into q)
#pragma unroll
      for (int r = 0; r < 4; ++r) {
        float m = S[0][r];
#pragma unroll
        for (int h = 1; h < 16; ++h) m = fmaxf(m, S[h][r]);
        float sum = 0.f;
#pragma unroll
        for (int h = 0; h < 16; ++h) {
          float e = __expf(S[h][r] - m);
          S[h][r] = e;
          sum += e;
        }
        float rinv = 1.0f / sum;
        const int qq = quad * 4 + r;
#pragma unroll
        for (int h = 0; h < 16; ++h) {
          union { float f; u32 u; } z; z.f = S[h][r] * rinv;
          Ws[h][qq][lo16] = (u16)((z.u + 0x8000u) >> 16);
        }
      }
    }
    __syncthreads();

    // ---- Phase B: PV MFMAs, head = wave ----
    {
      const int h = wave;
      short8 aw = *(const short8*)&Ws[h][lo16][quad * 8];  // k>=16 are zeros
      const int vr = (quad & 1) * 8;  // B rows for k<16; k>=16 contribute x0
#pragma unroll
      for (int dt = 0; dt < 4; ++dt) {
        const int col = h * 64 + dt * 16 + lo16;
        short8 bv;
#pragma unroll
        for (int j = 0; j < 8; ++j) bv[j] = (short)Vs[vr + j][col];
        cacc[dt] = __builtin_amdgcn_mfma_f32_16x16x32_bf16(aw, bv, cacc[dt], 0, 0, 0);
      }
    }
    __syncthreads();
  }

  // write ctx (C/D layout: row=quad*4+r, col=lo16)
  {
    const int h = wave;
    u16* crow = ctx + (size_t)(qrow0 + quad * 4) * D_ + h * 64 + lo16;
#pragma unroll
    for (int dt = 0; dt < 4; ++dt)
#pragma unroll
      for (int r = 0; r < 4; ++r)
        crow[(size_t)r * D_ + dt * 16] = f2b(cacc[dt][r]);
  }
}

// ---------- (x [+ y]) -> LayerNorm (D=1024, one block per row) ----------
__device__ __forceinline__ float block_sum(float vv, float* sm) {
#pragma unroll
  for (int o = 32; o > 0; o >>= 1) vv += __shfl_down(vv, o);
  __syncthreads();
  if ((threadIdx.x & 63) == 0) sm[threadIdx.x >> 6] = vv;
  __syncthreads();
  return sm[0] + sm[1] + sm[2] + sm[3];
}

template<typename TX, bool HAS_Y, typename TO>
__global__ __launch_bounds__(256)
void add_ln(const TX* __restrict__ x, const u16* __restrict__ y,
            const float* __restrict__ g, const float* __restrict__ bta,
            TO* __restrict__ out)
{
  __shared__ float sm[4];
  const int row = blockIdx.x;
  const int t   = threadIdx.x;
  const size_t base = (size_t)row * D_ + t * 4;

  float s[4];
  if (sizeof(TX) == 4) {
    float4 xv = *(const float4*)((const float*)x + base);
    s[0] = xv.x; s[1] = xv.y; s[2] = xv.z; s[3] = xv.w;
  } else {
    uint2 xv = *(const uint2*)((const u16*)x + base);
    s[0] = b2f(xv.x & 0xffffu);
    s[1] = b2f(xv.x >> 16);
    s[2] = b2f(xv.y & 0xffffu);
    s[3] = b2f(xv.y >> 16);
  }
  if (HAS_Y) {
    uint2 yv = *(const uint2*)(y + base);
    s[0] += b2f(yv.x & 0xffffu);
    s[1] += b2f(yv.x >> 16);
    s[2] += b2f(yv.y & 0xffffu);
    s[3] += b2f(yv.y >> 16);
  }

  float loc = s[0] + s[1] + s[2] + s[3];
  float tot = block_sum(loc, sm);
  float mean = tot * (1.f / 1024.f);
  float d0 = s[0] - mean, d1 = s[1] - mean, d2 = s[2] - mean, d3 = s[3] - mean;
  float sq = d0 * d0 + d1 * d1 + d2 * d2 + d3 * d3;
  float tv = block_sum(sq, sm);
  float rstd = rsqrtf(tv * (1.f / 1024.f) + 1e-5f);

  float4 gv = *(const float4*)(g + t * 4);
  float4 bv = *(const float4*)(bta + t * 4);
  float o0 = d0 * rstd * gv.x + bv.x;
  float o1 = d1 * rstd * gv.y + bv.y;
  float o2 = d2 * rstd * gv.z + bv.z;
  float o3 = d3 * rstd * gv.w + bv.w;
  if (sizeof(TO) == 4) {
    *(float4*)((float*)out + base) = make_float4(o0, o1, o2, o3);
  } else {
    uint2 ov;
    ov.x = (u32)f2b(o0) | ((u32)f2b(o1) << 16);
    ov.y = (u32)f2b(o2) | ((u32)f2b(o3) << 16);
    *(uint2*)((u16*)out + base) = ov;
  }
}

// ---------- launch ----------
// Inputs fp32, output fp32. Intermediates bf16 in ws. Peak ws = 33.55 MB.
//   slot0: q -> ao -> h1[0] | slot1: k -> h1[1] | slot2: v -> h1[2]
//   slot3: ctx -> h1[3] | d_out(fp32): x1 -> z -> final LN in-place
extern "C" void kernel_launch(void* const* d_in, const int* in_sizes, int n_in,
                              void* d_out, int out_size, void* d_ws, size_t ws_size,
                              hipStream_t stream) {
  const float* x     = (const float*)d_in[0];
  const float* wq    = (const float*)d_in[1];
  const float* bq    = (const float*)d_in[2];
  const float* wk    = (const float*)d_in[3];
  const float* bk    = (const float*)d_in[4];
  const float* wv    = (const float*)d_in[5];
  const float* bv    = (const float*)d_in[6];
  const float* wo    = (const float*)d_in[7];
  const float* bo    = (const float*)d_in[8];
  const float* g1    = (const float*)d_in[9];
  const float* beta1 = (const float*)d_in[10];
  const float* w1    = (const float*)d_in[11];
  const float* b1    = (const float*)d_in[12];
  const float* w2    = (const float*)d_in[13];
  const float* b2    = (const float*)d_in[14];
  const float* g2    = (const float*)d_in[15];
  const float* beta2 = (const float*)d_in[16];
  float* outF = (float*)d_out;

  u16* ws = (u16*)d_ws;
  const size_t MD = (size_t)M_ * D_;
  u16* q   = ws + 0 * MD;
  u16* kb  = ws + 1 * MD;
  u16* vb  = ws + 2 * MD;
  u16* ctx = ws + 3 * MD;
  u16* ao  = ws + 0 * MD;
  float* x1 = outF;
  u16* h1  = ws + 0 * MD;
  float* z  = outF;

  dim3 blk(256);
  // QKV projections; 1/sqrt(dk)=0.125 folded into q
  gemm_bias<false, false><<<dim3(D_ / 128, M_ / 128), blk, 0, stream>>>(x, wq, bq, (const u16*)nullptr, q,  M_, D_, D_, 0.125f);
  gemm_bias<false, false><<<dim3(D_ / 128, M_ / 128), blk, 0, stream>>>(x, wk, bk, (const u16*)nullptr, kb, M_, D_, D_, 1.0f);
  gemm_bias<false, false><<<dim3(D_ / 128, M_ / 128), blk, 0, stream>>>(x, wv, bv, (const u16*)nullptr, vb, M_, D_, D_, 1.0f);
  // fused MFMA attention (head-axis softmax)
  attention_mfma<<<dim3(M_ / 16), dim3(1024), 0, stream>>>(q, kb, vb, ctx);
  // output projection
  gemm_bias<false, false><<<dim3(D_ / 128, M_ / 128), blk, 0, stream>>>(ctx, wo, bo, (const u16*)nullptr, ao, M_, D_, D_, 1.0f);
  // x1 = LN(x + attn_out)
  add_ln<float, true, float><<<dim3(M_), blk, 0, stream>>>(x, ao, g1, beta1, x1);
  // FFN1: h1 = relu(x1 @ w1 + b1)
  gemm_bias<true, false><<<dim3(DFF_ / 128, M_ / 128), blk, 0, stream>>>(x1, w1, b1, (const u16*)nullptr, h1, M_, DFF_, D_, 1.0f);
  // FFN2 + residual x1, in-place over d_out
  gemm_bias<false, true><<<dim3(D_ / 128, M_ / 128), blk, 0, stream>>>(h1, w2, b2, (const float*)x1, z, M_, D_, DFF_, 1.0f);
  // out = LN(z), in-place on d_out
  add_ln<float, false, float><<<dim3(M_), blk, 0, stream>>>(z, (const u16*)nullptr, g2, beta2, outF);
}

// Round 8
// 937.800 us; speedup vs baseline: 3.9835x; 2.5455x over previous
//
#include <hip/hip_runtime.h>
#include <stdint.h>

// Problem constants
#define B_   2
#define S_   2048
#define D_   1024
#define H_   16
#define DK_  64
#define DFF_ 4096
#define M_   (B_ * S_)   // 4096 rows total

typedef unsigned short u16;
typedef unsigned int   u32;
typedef __attribute__((ext_vector_type(8))) short short8;  // 8 bf16 (4 VGPRs)
typedef __attribute__((ext_vector_type(4))) float f32x4;   // MFMA C/D

// ---------- bf16 <-> f32 helpers ----------
__device__ __forceinline__ float b2f(u16 u) {
  union { u32 i; float f; } z; z.i = ((u32)u) << 16; return z.f;
}
__device__ __forceinline__ u16 f2b(float f) {
  union { float f; u32 i; } z; z.f = f;
  u32 x = z.i;
  u32 r = (x + 0x7fffu + ((x >> 16) & 1u)) >> 16;
  return (u16)r;
}

// load 4 consecutive elems as fp32 from fp32 or bf16 backing
__device__ __forceinline__ void load4(const float* p, float* f) {
  float4 v = *(const float4*)p;
  f[0] = v.x; f[1] = v.y; f[2] = v.z; f[3] = v.w;
}
__device__ __forceinline__ void load4(const u16* p, float* f) {
  uint2 v = *(const uint2*)p;
  f[0] = b2f(v.x & 0xffffu); f[1] = b2f(v.x >> 16);
  f[2] = b2f(v.y & 0xffffu); f[3] = b2f(v.y >> 16);
}
__device__ __forceinline__ void tstore(float* p, float v) { *p = v; }
__device__ __forceinline__ void tstore(u16* p, float v)   { *p = f2b(v); }
__device__ __forceinline__ float tload(const float* p) { return *p; }
__device__ __forceinline__ float tload(const u16* p)   { return b2f(*p); }

// ---------- MFMA GEMM: C[M,N] = (A@W + bias)*oscale (+ReLU) (+res) ----------
// A: fp32 or bf16 global. W/bias: fp32 global. C/res: fp32 or bf16.
// 128x128 tile, BK=32, 256 threads = 4 waves, each wave 64x64 (4x4 MFMA
// tiles of 16x16x32 bf16). fp32->bf16 conversion happens in staging.
// LDS rows are 40 u16 = 80 B (20 dwords, gcd(20,32)=4 -> rotating banks).
// MFMA layouts (verified round 7): A[m=lane&15][k=quad*8+j],
// B[n=lane&15][k=quad*8+j], D[row=quad*4+r][col=lane&15], row = A's m.
template<bool RELU, bool RES, typename TA, typename TO>
__global__ __launch_bounds__(256)
void gemm_mfma(const TA* __restrict__ A, const float* __restrict__ W,
               const float* __restrict__ bias, const TO* __restrict__ res,
               TO* __restrict__ C, int M, int N, int K, float oscale)
{
  __shared__ u16 As[128][40];   // [m][k] k-contiguous
  __shared__ u16 Bs[128][40];   // [n][k] k-contiguous (W transposed)

  const int tid  = threadIdx.x;
  const int wave = tid >> 6;
  const int lane = tid & 63;
  const int lo16 = lane & 15;
  const int quad = lane >> 4;
  const int row0 = blockIdx.y * 128;
  const int col0 = blockIdx.x * 128;
  const int mb   = (wave & 1) * 64;
  const int nb   = (wave >> 1) * 64;

  f32x4 acc[4][4];
#pragma unroll
  for (int i = 0; i < 4; ++i)
#pragma unroll
    for (int j = 0; j < 4; ++j) acc[i][j] = (f32x4){0.f, 0.f, 0.f, 0.f};

  // A staging: thread covers rows {rg, rg+32, rg+64, rg+96}, k-quarter kq*4
  const int a_kq = tid & 7;
  const int a_rg = tid >> 3;
  // W staging: thread covers col b_n, k-half b_h*16
  const int b_n = tid & 127;
  const int b_h = tid >> 7;

  for (int k0 = 0; k0 < K; k0 += 32) {
    // stage A (fp32/bf16 -> bf16)
#pragma unroll
    for (int rep = 0; rep < 4; ++rep) {
      const int r = a_rg + rep * 32;
      float f[4];
      load4(A + (size_t)(row0 + r) * K + k0 + a_kq * 4, f);
      uint2 pk;
      pk.x = (u32)f2b(f[0]) | ((u32)f2b(f[1]) << 16);
      pk.y = (u32)f2b(f[2]) | ((u32)f2b(f[3]) << 16);
      *(uint2*)&As[r][a_kq * 4] = pk;
    }
    // stage W transposed (fp32 -> bf16): 16 coalesced scalar loads
    {
      u16 wt[16];
#pragma unroll
      for (int i = 0; i < 16; ++i)
        wt[i] = f2b(W[(size_t)(k0 + b_h * 16 + i) * N + col0 + b_n]);
      uint4 p0, p1;
      p0.x = (u32)wt[0]  | ((u32)wt[1]  << 16);
      p0.y = (u32)wt[2]  | ((u32)wt[3]  << 16);
      p0.z = (u32)wt[4]  | ((u32)wt[5]  << 16);
      p0.w = (u32)wt[6]  | ((u32)wt[7]  << 16);
      p1.x = (u32)wt[8]  | ((u32)wt[9]  << 16);
      p1.y = (u32)wt[10] | ((u32)wt[11] << 16);
      p1.z = (u32)wt[12] | ((u32)wt[13] << 16);
      p1.w = (u32)wt[14] | ((u32)wt[15] << 16);
      *(uint4*)&Bs[b_n][b_h * 16] = (b_h == 0) ? p0 : p0;  // placeholder overwritten below
      *(uint4*)&Bs[b_n][b_h * 16] = p0;
      *(uint4*)&Bs[b_n][b_h * 16 + 8] = p1;
    }
    __syncthreads();

    short8 af[4], bf[4];
#pragma unroll
    for (int mi = 0; mi < 4; ++mi)
      af[mi] = *(const short8*)&As[mb + mi * 16 + lo16][quad * 8];
#pragma unroll
    for (int ni = 0; ni < 4; ++ni)
      bf[ni] = *(const short8*)&Bs[nb + ni * 16 + lo16][quad * 8];
#pragma unroll
    for (int mi = 0; mi < 4; ++mi)
#pragma unroll
      for (int ni = 0; ni < 4; ++ni)
        acc[mi][ni] = __builtin_amdgcn_mfma_f32_16x16x32_bf16(af[mi], bf[ni], acc[mi][ni], 0, 0, 0);
    __syncthreads();
  }

  // epilogue
  float bv[4];
#pragma unroll
  for (int ni = 0; ni < 4; ++ni) bv[ni] = bias[col0 + nb + ni * 16 + lo16];
#pragma unroll
  for (int mi = 0; mi < 4; ++mi) {
#pragma unroll
    for (int ni = 0; ni < 4; ++ni) {
      const int col = col0 + nb + ni * 16 + lo16;
#pragma unroll
      for (int r = 0; r < 4; ++r) {
        const int row = row0 + mb + mi * 16 + quad * 4 + r;
        float vv = (acc[mi][ni][r] + bv[ni]) * oscale;
        if (RELU) vv = fmaxf(vv, 0.f);
        if (RES)  vv += tload(res + (size_t)row * N + col);
        tstore(C + (size_t)row * N + col, vv);
      }
    }
  }
}

// ---------- MFMA attention, head-axis softmax, balanced phases ----------
// Block = 16 q-rows, 1024 threads (16 waves). T-block = 128 (16 iterations).
// Phase A: waves 0..7, wave w owns t-chunk [t0+w*16, +16): computes all 16
//   heads' scores via 2 MFMAs/head (Q,K frags from global), does the
//   head-axis softmax fully in-register (16 head values for a (q,t) live in
//   the same lane+reg across the 16 accumulators), writes bf16 weights to
//   Ws[16][16][128] (64 KB) with XOR swizzle pos = t_local ^ ((q&7)<<3)
//   (rows are 256 B -> swizzle restores b128 bank spread).
// Phase B: wave h computes ctx for head h: A-frag = aligned ds_read_b128
//   from Ws plane h (K=32 exact), B-frag = V gathered from global (L2-hot),
//   4 kc x 4 dt MFMAs per iteration.
__global__ __launch_bounds__(1024)
void attention_mfma(const u16* __restrict__ q, const u16* __restrict__ k,
                    const u16* __restrict__ v, u16* __restrict__ ctx)
{
  __shared__ __align__(16) u16 Ws[16][16][128];  // 65,536 B

  const int tid  = threadIdx.x;
  const int wave = tid >> 6;
  const int lane = tid & 63;
  const int lo16 = lane & 15;
  const int quad = lane >> 4;

  const int qrow0 = blockIdx.x * 16;
  const int batch = blockIdx.x >> 7;
  const u16* kbp = k + (size_t)batch * S_ * D_;
  const u16* vbp = v + (size_t)batch * S_ * D_;

  f32x4 cacc[4];
#pragma unroll
  for (int i = 0; i < 4; ++i) cacc[i] = (f32x4){0.f, 0.f, 0.f, 0.f};

  // phase-A Q fragment base (row = q-index, within-row offset = quad*8)
  const u16* qrow = q + (size_t)(qrow0 + lo16) * D_ + quad * 8;

  for (int t0 = 0; t0 < S_; t0 += 128) {
    // ---- Phase A ----
    if (wave < 8) {
      const int tloc = wave * 16;               // t-chunk base within block
      const u16* krow = kbp + (size_t)(t0 + tloc + lo16) * D_ + quad * 8;
      f32x4 S[16];
#pragma unroll
      for (int h = 0; h < 16; ++h) {
        short8 a0 = *(const short8*)(qrow + h * 64);
        short8 b0 = *(const short8*)(krow + h * 64);
        short8 a1 = *(const short8*)(qrow + h * 64 + 32);
        short8 b1 = *(const short8*)(krow + h * 64 + 32);
        f32x4 s = (f32x4){0.f, 0.f, 0.f, 0.f};
        s = __builtin_amdgcn_mfma_f32_16x16x32_bf16(a0, b0, s, 0, 0, 0);
        s = __builtin_amdgcn_mfma_f32_16x16x32_bf16(a1, b1, s, 0, 0, 0);
        S[h] = s;
      }
      // in-register softmax over heads (1/sqrt(dk) pre-folded into q)
#pragma unroll
      for (int r = 0; r < 4; ++r) {
        float m = S[0][r];
#pragma unroll
        for (int h = 1; h < 16; ++h) m = fmaxf(m, S[h][r]);
        float sum = 0.f;
#pragma unroll
        for (int h = 0; h < 16; ++h) {
          float e = __expf(S[h][r] - m);
          S[h][r] = e;
          sum += e;
        }
        float rinv = 1.0f / sum;
        const int qq = quad * 4 + r;            // q-index (C/D row)
        const int pos = (tloc + lo16) ^ ((qq & 7) << 3);  // swizzled t slot
#pragma unroll
        for (int h = 0; h < 16; ++h) {
          union { float f; u32 u; } z; z.f = S[h][r] * rinv;
          Ws[h][qq][pos] = (u16)((z.u + 0x8000u) >> 16);
        }
      }
    }
    __syncthreads();

    // ---- Phase B: head = wave ----
    {
      const int h = wave;
#pragma unroll
      for (int kc = 0; kc < 4; ++kc) {
        const int kbase = kc * 32 + quad * 8;   // un-swizzled t-local
        const int ksw   = kbase ^ ((lo16 & 7) << 3);
        short8 aw = *(const short8*)&Ws[h][lo16][ksw];
        const u16* vp0 = vbp + (size_t)(t0 + kbase) * D_ + h * 64 + lo16;
#pragma unroll
        for (int dt = 0; dt < 4; ++dt) {
          const u16* vp = vp0 + dt * 16;
          short8 bv;
#pragma unroll
          for (int j = 0; j < 8; ++j) bv[j] = (short)vp[(size_t)j * D_];
          cacc[dt] = __builtin_amdgcn_mfma_f32_16x16x32_bf16(aw, bv, cacc[dt], 0, 0, 0);
        }
      }
    }
    __syncthreads();
  }

  // write ctx (D row = q = quad*4+r, col = lo16), head = wave
  {
    const int h = wave;
    u16* crow = ctx + (size_t)(qrow0 + quad * 4) * D_ + h * 64 + lo16;
#pragma unroll
    for (int dt = 0; dt < 4; ++dt)
#pragma unroll
      for (int r = 0; r < 4; ++r)
        crow[(size_t)r * D_ + dt * 16] = f2b(cacc[dt][r]);
  }
}

// ---------- (x [+ y]) -> LayerNorm (D=1024, one block per row) ----------
__device__ __forceinline__ float block_sum(float vv, float* sm) {
#pragma unroll
  for (int o = 32; o > 0; o >>= 1) vv += __shfl_down(vv, o);
  __syncthreads();
  if ((threadIdx.x & 63) == 0) sm[threadIdx.x >> 6] = vv;
  __syncthreads();
  return sm[0] + sm[1] + sm[2] + sm[3];
}

template<typename TX, bool HAS_Y, typename TO>
__global__ __launch_bounds__(256)
void add_ln(const TX* __restrict__ x, const u16* __restrict__ y,
            const float* __restrict__ g, const float* __restrict__ bta,
            TO* __restrict__ out)
{
  __shared__ float sm[4];
  const int row = blockIdx.x;
  const int t   = threadIdx.x;
  const size_t base = (size_t)row * D_ + t * 4;

  float s[4];
  load4(x + base, s);
  if (HAS_Y) {
    float yv[4];
    load4(y + base, yv);
    s[0] += yv[0]; s[1] += yv[1]; s[2] += yv[2]; s[3] += yv[3];
  }

  float loc = s[0] + s[1] + s[2] + s[3];
  float tot = block_sum(loc, sm);
  float mean = tot * (1.f / 1024.f);
  float d0 = s[0] - mean, d1 = s[1] - mean, d2 = s[2] - mean, d3 = s[3] - mean;
  float sq = d0 * d0 + d1 * d1 + d2 * d2 + d3 * d3;
  float tv = block_sum(sq, sm);
  float rstd = rsqrtf(tv * (1.f / 1024.f) + 1e-5f);

  float4 gv = *(const float4*)(g + t * 4);
  float4 bv = *(const float4*)(bta + t * 4);
  float o0 = d0 * rstd * gv.x + bv.x;
  float o1 = d1 * rstd * gv.y + bv.y;
  float o2 = d2 * rstd * gv.z + bv.z;
  float o3 = d3 * rstd * gv.w + bv.w;
  if (sizeof(TO) == 4) {
    *(float4*)((float*)out + base) = make_float4(o0, o1, o2, o3);
  } else {
    uint2 ov;
    ov.x = (u32)f2b(o0) | ((u32)f2b(o1) << 16);
    ov.y = (u32)f2b(o2) | ((u32)f2b(o3) << 16);
    *(uint2*)((u16*)out + base) = ov;
  }
}

// ---------- launch ----------
// Inputs fp32, output fp32. Intermediates bf16 in ws. Peak ws = 33.55 MB.
//   slot0: q -> ao -> h1[0] | slot1: k -> h1[1] | slot2: v -> h1[2]
//   slot3: ctx -> h1[3] | d_out(fp32): x1 -> z -> final LN in-place
extern "C" void kernel_launch(void* const* d_in, const int* in_sizes, int n_in,
                              void* d_out, int out_size, void* d_ws, size_t ws_size,
                              hipStream_t stream) {
  const float* x     = (const float*)d_in[0];
  const float* wq    = (const float*)d_in[1];
  const float* bq    = (const float*)d_in[2];
  const float* wk    = (const float*)d_in[3];
  const float* bk    = (const float*)d_in[4];
  const float* wv    = (const float*)d_in[5];
  const float* bv    = (const float*)d_in[6];
  const float* wo    = (const float*)d_in[7];
  const float* bo    = (const float*)d_in[8];
  const float* g1    = (const float*)d_in[9];
  const float* beta1 = (const float*)d_in[10];
  const float* w1    = (const float*)d_in[11];
  const float* b1    = (const float*)d_in[12];
  const float* w2    = (const float*)d_in[13];
  const float* b2    = (const float*)d_in[14];
  const float* g2    = (const float*)d_in[15];
  const float* beta2 = (const float*)d_in[16];
  float* outF = (float*)d_out;

  u16* ws = (u16*)d_ws;
  const size_t MD = (size_t)M_ * D_;
  u16* q   = ws + 0 * MD;
  u16* kb  = ws + 1 * MD;
  u16* vb  = ws + 2 * MD;
  u16* ctx = ws + 3 * MD;
  u16* ao  = ws + 0 * MD;
  float* x1 = outF;
  u16* h1  = ws + 0 * MD;
  float* z  = outF;

  dim3 blk(256);
  // QKV projections; 1/sqrt(dk)=0.125 folded into q
  gemm_mfma<false, false><<<dim3(D_ / 128, M_ / 128), blk, 0, stream>>>(x, wq, bq, (const u16*)nullptr, q,  M_, D_, D_, 0.125f);
  gemm_mfma<false, false><<<dim3(D_ / 128, M_ / 128), blk, 0, stream>>>(x, wk, bk, (const u16*)nullptr, kb, M_, D_, D_, 1.0f);
  gemm_mfma<false, false><<<dim3(D_ / 128, M_ / 128), blk, 0, stream>>>(x, wv, bv, (const u16*)nullptr, vb, M_, D_, D_, 1.0f);
  // fused MFMA attention (head-axis softmax)
  attention_mfma<<<dim3(M_ / 16), dim3(1024), 0, stream>>>(q, kb, vb, ctx);
  // output projection
  gemm_mfma<false, false><<<dim3(D_ / 128, M_ / 128), blk, 0, stream>>>(ctx, wo, bo, (const u16*)nullptr, ao, M_, D_, D_, 1.0f);
  // x1 = LN(x + attn_out)
  add_ln<float, true, float><<<dim3(M_), blk, 0, stream>>>(x, ao, g1, beta1, x1);
  // FFN1: h1 = relu(x1 @ w1 + b1)
  gemm_mfma<true, false><<<dim3(DFF_ / 128, M_ / 128), blk, 0, stream>>>(x1, w1, b1, (const u16*)nullptr, h1, M_, DFF_, D_, 1.0f);
  // FFN2 + residual x1, in-place over d_out
  gemm_mfma<false, true><<<dim3(D_ / 128, M_ / 128), blk, 0, stream>>>(h1, w2, b2, (const float*)x1, z, M_, D_, DFF_, 1.0f);
  // out = LN(z), in-place on d_out
  add_ln<float, false, float><<<dim3(M_), blk, 0, stream>>>(z, (const u16*)nullptr, g2, beta2, outF);
}